// Round 12
// baseline (344.817 us; speedup 1.0000x reference)
//
#include <hip/hip_runtime.h>

// ---------------------------------------------------------------------------
// Self_Attention_30193620091602  (N=256, A=1024, K_DIM=1), fp32 in/out.
// R12: R11 with k_qvkl's weight double-buffer REMOVED (sW[2]->sW[1]):
// LDS 128KB -> 80KB exactly -> 2 blocks/CU at the SAME 512-thread geometry.
// Weight DMA is now drained in-phase (vmcnt(0) before the MFMA barrier);
// the re-exposed ~900cy/phase is covered by the co-resident block's MFMA
// (m114 TLP co-scheduling) — the lever every schedule-level attempt missed.
// All addresses and arithmetic byte-identical to R11 (only buffer count and
// wait discipline changed; no registers live across barriers; no geometry
// change). K3/K4/K5/k_split3: R11-verbatim.
// Scratch: d_out[0..134MB) holds qT/v/attT (dead before K5 overwrites d_out);
// d_ws holds om + split weights + klT (~37 MB).
// ---------------------------------------------------------------------------

typedef unsigned short u16;
typedef unsigned int   uint;
using f32x4  = __attribute__((ext_vector_type(4))) float;
using bf16x8 = __attribute__((ext_vector_type(8))) short;
using u16x4  = __attribute__((ext_vector_type(4))) u16;

#define DEVI static __device__ __forceinline__

DEVI u16 f2bf(float f){
  union { float f; uint u; } v; v.f = f;
  uint r = v.u + 0x7fffu + ((v.u >> 16) & 1u);   // round-to-nearest-even
  return (u16)(r >> 16);
}
DEVI float bf2f(u16 h){
  union { uint u; float f; } v; v.u = ((uint)h) << 16;
  return v.f;
}

typedef const uint __attribute__((address_space(1)))* as1_cuintp;
typedef uint __attribute__((address_space(3)))* as3_uintp;

DEVI void gl_lds16(const void* g, void* l){
  __builtin_amdgcn_global_load_lds((as1_cuintp)g, (as3_uintp)l, 16, 0, 0);
}

// Stage ROWS x 64 bf16 tile (rowStride elems in global) into LDS, NW waves.
// LDS layout: elem(row,k) at row*64 + ((k/8 ^ (row&7))*8 + k%8)  (16B-chunk
// XOR swizzle; global_load_lds writes linearly, so the SOURCE is pre-swizzled).
template<int ROWS, int NW>
DEVI void stage_tile(const u16* __restrict__ g, long long rowStride,
                     u16* lds, int lane, int wave){
  constexpr int NLD = ROWS >> 3;            // 1KB wave-loads
  #pragma unroll
  for (int j = 0; j < NLD/NW; ++j){
    int r0  = (wave + NW*j) << 3;
    int row = r0 + (lane >> 3);
    const u16* src = g + (long long)row * rowStride
                       + (((lane & 7) ^ (lane >> 3)) << 3);
    gl_lds16(src, lds + r0 * 64);
  }
}

// MFMA A/B fragment read from the swizzled [*,64] LDS tile.
DEVI bf16x8 ldfrag(const u16* s, int rbase, int kk, int lane){
  int row = rbase + (lane & 15);
  int c   = (kk << 2) + (lane >> 4);
  return *(const bf16x8*)(s + row*64 + ((c ^ (row & 7)) << 3));
}

// ---------------------------------------------------------------------------
// k_qvkl: fused q(split) + v + klin.  512 thr, 8 waves 2x4; per phase a wave
// computes 64 rows x 32 cols.  Single-buffered weights (48KB) -> 80KB LDS ->
// 2 blocks/CU; in-phase weight drain; cross-block TLP hides the DMA latency.
// ---------------------------------------------------------------------------
__global__ __launch_bounds__(512, 2)
void k_qvkl(const float* __restrict__ x,
            const u16* __restrict__ Wqh, const u16* __restrict__ Wql,
            const u16* __restrict__ Wvh,
            const float* __restrict__ Wk, const float* __restrict__ bk,
            const float* __restrict__ bq, const float* __restrict__ bv,
            u16* __restrict__ qTh, u16* __restrict__ qTl,
            u16* __restrict__ vout,
            u16* __restrict__ klTh, u16* __restrict__ klTl)
{
  __shared__ __align__(16) u16 sX [128*64];     // 16KB  x hi
  __shared__ __align__(16) u16 sXl[128*64];     // 16KB  x lo
  __shared__ __align__(16) u16 sW [3*128*64];   // 48KB: [Wqh|Wql|Wvh] half-N
                                                // total 80KB -> 2 blocks/CU

  const int tid  = threadIdx.x;
  const int lane = tid & 63;
  const int wave = tid >> 6;     // 0..7
  const int wm   = wave >> 2;    // 0..1  row-half
  const int wn   = wave & 3;     // 0..3  col-slice within a half
  const int tileM = blockIdx.x << 7;

  f32x4 qacc[4][4], vacc[4][4];  // [mt][ntg], ntg = h*2 + ntl
  #pragma unroll
  for (int i=0;i<4;i++)
    #pragma unroll
    for (int j=0;j<4;j++){
      qacc[i][j][0]=0.f; qacc[i][j][1]=0.f; qacc[i][j][2]=0.f; qacc[i][j][3]=0.f;
      vacc[i][j][0]=0.f; vacc[i][j][1]=0.f; vacc[i][j][2]=0.f; vacc[i][j][3]=0.f;
    }
  float kacc[4] = {0.f, 0.f, 0.f, 0.f};

  for (int kt = 0; kt < 1024; kt += 64){
    #pragma unroll
    for (int h = 0; h < 2; ++h){          // h compile-time via unroll (rule #20)
      // --- x loads for this kt (h==0 only), ISSUED BEFORE the stage so the
      //     compiler's xr-wait (vmcnt(6)) leaves this phase's W DMA in flight
      //     during the convert.
      f32x4 xr[4];
      if (h == 0){
        #pragma unroll
        for (int j=0;j<4;j++){
          int f = tid + (j << 9);
          xr[j] = *(const f32x4*)(x + (long long)(tileM + (f >> 4))*1024
                                  + kt + ((f & 15) << 2));
        }
        __builtin_amdgcn_sched_barrier(0);   // pin: xr issue before stage issue
      }
      // --- stage THIS phase's weights (6 gl_lds/wave) into the single buffer
      stage_tile<128,8>(Wqh + (h << 7)*1024 + kt, 1024, sW,         lane, wave);
      stage_tile<128,8>(Wql + (h << 7)*1024 + kt, 1024, sW + 8192,  lane, wave);
      stage_tile<128,8>(Wvh + (h << 7)*1024 + kt, 1024, sW + 16384, lane, wave);
      // --- convert x -> sX/sXl, accumulate klin (verbatim R4 math)
      if (h == 0){
        #pragma unroll
        for (int j=0;j<4;j++){
          int f   = tid + (j << 9);
          int row = f >> 4;
          int c16 = f & 15;
          f32x4 t = xr[j];
          u16x4 h4, l4;
          #pragma unroll
          for (int e=0;e<4;e++){
            u16 hh = f2bf(t[e]);
            h4[e] = hh;
            l4[e] = f2bf(t[e] - bf2f(hh));
          }
          int off = row*64 + (((c16 >> 1) ^ (row & 7)) << 3) + ((c16 & 1) << 2);
          *(u16x4*)(sX  + off) = h4;
          *(u16x4*)(sXl + off) = l4;
          f32x4 w = *(const f32x4*)(Wk + kt + (c16 << 2));
          kacc[j] += t[0]*w[0] + t[1]*w[1] + t[2]*w[2] + t[3]*w[3];
        }
      }
      // --- pre-MFMA barrier: this phase's weights + converts fully landed.
      asm volatile("s_waitcnt vmcnt(0) lgkmcnt(0)" ::: "memory");
      __builtin_amdgcn_s_barrier();
      __builtin_amdgcn_sched_barrier(0);

      // --- MFMA for this half: wave covers cols h*128 + wn*32 + ntl*16
      {
        const u16* wb = sW;
        #pragma unroll
        for (int kk=0;kk<2;kk++){
          bf16x8 a[4], al[4];
          #pragma unroll
          for (int i=0;i<4;i++){
            a[i]  = ldfrag(sX , wm*64 + i*16, kk, lane);
            al[i] = ldfrag(sXl, wm*64 + i*16, kk, lane);
          }
          {
            bf16x8 b[2];
            #pragma unroll
            for (int i=0;i<2;i++) b[i] = ldfrag(wb, wn*32 + i*16, kk, lane);
            #pragma unroll
            for (int mt=0;mt<4;mt++)
              #pragma unroll
              for (int ntl=0;ntl<2;ntl++){
                qacc[mt][(h<<1)|ntl] = __builtin_amdgcn_mfma_f32_16x16x32_bf16(a[mt],  b[ntl], qacc[mt][(h<<1)|ntl], 0,0,0);
                qacc[mt][(h<<1)|ntl] = __builtin_amdgcn_mfma_f32_16x16x32_bf16(al[mt], b[ntl], qacc[mt][(h<<1)|ntl], 0,0,0);
              }
          }
          {
            bf16x8 b[2];
            #pragma unroll
            for (int i=0;i<2;i++) b[i] = ldfrag(wb + 8192, wn*32 + i*16, kk, lane);
            #pragma unroll
            for (int mt=0;mt<4;mt++)
              #pragma unroll
              for (int ntl=0;ntl<2;ntl++)
                qacc[mt][(h<<1)|ntl] = __builtin_amdgcn_mfma_f32_16x16x32_bf16(a[mt], b[ntl], qacc[mt][(h<<1)|ntl], 0,0,0);
          }
          {
            bf16x8 b[2];
            #pragma unroll
            for (int i=0;i<2;i++) b[i] = ldfrag(wb + 16384, wn*32 + i*16, kk, lane);
            #pragma unroll
            for (int mt=0;mt<4;mt++)
              #pragma unroll
              for (int ntl=0;ntl<2;ntl++)
                vacc[mt][(h<<1)|ntl] = __builtin_amdgcn_mfma_f32_16x16x32_bf16(a[mt], b[ntl], vacc[mt][(h<<1)|ntl], 0,0,0);
          }
        }
      }
      // --- post-MFMA barrier: all waves' LDS reads done before next phase's
      //     DMA/convert overwrites sW/sX.
      asm volatile("s_waitcnt lgkmcnt(0)" ::: "memory");
      __builtin_amdgcn_s_barrier();
      __builtin_amdgcn_sched_barrier(0);
    }
  }

  // klin: reduce over 16-lane groups (each group owns one row per j), store T
  #pragma unroll
  for (int j=0;j<4;j++){
    #pragma unroll
    for (int m=1;m<16;m<<=1) kacc[j] += __shfl_xor(kacc[j], m, 64);
  }
  if ((lane & 15) == 0){
    #pragma unroll
    for (int j=0;j<4;j++){
      int f = tid + (j << 9);
      int r = tileM + (f >> 4);
      float kv = kacc[j] + bk[0];
      u16 hh = f2bf(kv);
      klTh[(r & 255)*256 + (r >> 8)] = hh;
      klTl[(r & 255)*256 + (r >> 8)] = f2bf(kv - bf2f(hh));
    }
  }

  // epilogue: C/D frag col = lane&15, row = (lane>>4)*4 + reg
  // cols: gc = (ntg>>1)*128 + wn*32 + (ntg&1)*16 + (lane&15)
  #pragma unroll
  for (int mt=0;mt<4;mt++)
    #pragma unroll
    for (int ntg=0;ntg<4;ntg++){
      const int gr = tileM + wm*64 + mt*16 + ((lane >> 4) << 2);
      const int gc = ((ntg >> 1) << 7) + wn*32 + ((ntg & 1) << 4) + (lane & 15);
      // qT: transposed hi/lo pair, 4 consecutive m -> 8B store (R1 WMODE=2)
      {
        const int bidx = gr >> 8, m = gr & 255;
        const long long off = ((long long)bidx << 16) + ((long long)gc << 8) + m;
        const float bb = bq[gc];
        u16x4 h4, l4;
        f32x4 v = qacc[mt][ntg];
        #pragma unroll
        for (int r=0;r<4;r++){
          float fq = v[r] + bb;
          u16 hh = f2bf(fq);
          h4[r] = hh;
          l4[r] = f2bf(fq - bf2f(hh));
        }
        *(u16x4*)(qTh + off) = h4;
        *(u16x4*)(qTl + off) = l4;
      }
      // v: natural bf16 (R1 WMODE=1)
      {
        const float bb = bv[gc];
        u16* o = vout + (long long)gr * 256 + gc;
        f32x4 v = vacc[mt][ntg];
        #pragma unroll
        for (int r=0;r<4;r++) o[(long long)r * 256] = f2bf(v[r] + bb);
      }
    }
}

// ---------------------------------------------------------------------------
// Generic GEMM: C[M x N] = A[M x K] * B^T (B stored N x K) (+bias)
// WMODE: 0 = fp32 natural (+bias)   (out-proj)
//        1 = bf16 natural (+bias)   (om)
// SWZ:   0 = none
//        1 = K4 grouping: 4 blocks sharing (vh tile pair, attT[b]) -> 1 XCD
//        2 = K5 grouping: 8 tn-blocks sharing an A tile -> 1 XCD
// bStrideB: if nonzero, B is batched per b = row/256 (attT).
// ---------------------------------------------------------------------------
template<int WMODE, int SWZ>
__global__ __launch_bounds__(256, 2)
void k_gemm(const u16* __restrict__ Ag,
            const u16* __restrict__ Bhg,
            int N, int K, int tnCount, long long bStrideB,
            const float* __restrict__ bias,
            void* __restrict__ Co)
{
  __shared__ __align__(16) u16 sA[128*64];
  __shared__ __align__(16) u16 sB[128*64];

  const int tid  = threadIdx.x;
  const int lane = tid & 63;
  const int wave = tid >> 6;
  const int wm   = wave >> 1;
  const int wn   = wave & 1;

  int tm, tn;
  if (SWZ == 1){
    const int bid = blockIdx.x;
    const int xcd = bid & 7, r = bid >> 3;
    const int inner = r & 3, slot = r >> 2;
    const int b = slot*8 + xcd;
    tm = 2*b + (inner >> 1);
    tn = inner & 1;
  } else if (SWZ == 2){
    const int bid = blockIdx.x;
    const int xcd = bid & 7, r = bid >> 3;
    tn = r & 7;
    tm = (r >> 3)*8 + xcd;
  } else {
    tn = blockIdx.x % tnCount;
    tm = blockIdx.x / tnCount;
  }
  const int tileM = tm << 7;
  const int tileN = tn << 7;

  const long long bOff = bStrideB ? (long long)(tileM >> 8) * bStrideB : 0;
  const u16* Bh_t = Bhg + bOff + (long long)tileN * K;

  f32x4 acc[4][4];
  #pragma unroll
  for (int i=0;i<4;i++)
    #pragma unroll
    for (int j=0;j<4;j++){
      acc[i][j][0]=0.f; acc[i][j][1]=0.f; acc[i][j][2]=0.f; acc[i][j][3]=0.f;
    }

  for (int kt = 0; kt < K; kt += 64){
    stage_tile<128,4>(Ag + (long long)tileM * K + kt, K, sA, lane, wave);
    stage_tile<128,4>(Bh_t + kt, K, sB, lane, wave);
    __syncthreads();
    #pragma unroll
    for (int kk=0;kk<2;kk++){
      bf16x8 a[4], b[4];
      #pragma unroll
      for (int i=0;i<4;i++){
        a[i] = ldfrag(sA, wm*64 + i*16, kk, lane);
        b[i] = ldfrag(sB, wn*64 + i*16, kk, lane);
      }
      #pragma unroll
      for (int mt=0;mt<4;mt++)
        #pragma unroll
        for (int nt=0;nt<4;nt++)
          acc[mt][nt] = __builtin_amdgcn_mfma_f32_16x16x32_bf16(a[mt], b[nt], acc[mt][nt], 0,0,0);
    }
    __syncthreads();
  }

  #pragma unroll
  for (int mt=0;mt<4;mt++)
    #pragma unroll
    for (int nt=0;nt<4;nt++){
      const int gr = tileM + wm*64 + mt*16 + ((lane >> 4) << 2);
      const int gc = tileN + wn*64 + nt*16 + (lane & 15);
      const float bb = bias ? bias[gc] : 0.f;
      f32x4 v = acc[mt][nt];
      if (WMODE == 0){
        float* o = (float*)Co + (long long)gr * N + gc;
        #pragma unroll
        for (int r=0;r<4;r++) o[(long long)r * N] = v[r] + bb;
      } else {
        u16* o = (u16*)Co + (long long)gr * N + gc;
        #pragma unroll
        for (int r=0;r<4;r++) o[(long long)r * N] = f2bf(v[r] + bb);
      }
    }
}

// ---------------------------------------------------------------------------
// K3: logits[b,n,:] = sum_m klT[n][m] * qT[b][:,m]  (split 3-pass), then
// row-softmax over qq (full 256 in-block), store attT[b][qq][n] bf16.
// Block = (b, ntile) via XCD-grouping swizzle; LDS 80KB -> 2 blocks/CU.
// ---------------------------------------------------------------------------
__global__ __launch_bounds__(256, 2)
void k_logits(const u16* __restrict__ qTh, const u16* __restrict__ qTl,
              const u16* __restrict__ klTh, const u16* __restrict__ klTl,
              u16* __restrict__ attT)
{
  __shared__ __align__(16) union U {
    struct S { u16 Ah[64*64]; u16 Al[64*64]; u16 Bh[256*64]; u16 Bl[256*64]; } s; // 81920 B
    struct T { float L[64*258]; float rmax[64]; float rinv[64]; } t;              // 66560 B
  } u;                                                                            // 80 KB

  const int tid  = threadIdx.x;
  const int lane = tid & 63;
  const int wave = tid >> 6;
  // XCD-grouping swizzle: bid = xcd + 8*(ntile + 4*slot); b = slot*8 + xcd
  const int bid   = blockIdx.x;
  const int xcd   = bid & 7, r = bid >> 3;
  const int ntile = r & 3;
  const int b     = (r >> 2)*8 + xcd;

  f32x4 acc[4][4];
  #pragma unroll
  for (int i=0;i<4;i++)
    #pragma unroll
    for (int j=0;j<4;j++){
      acc[i][j][0]=0.f; acc[i][j][1]=0.f; acc[i][j][2]=0.f; acc[i][j][3]=0.f;
    }

  for (int kt=0; kt<256; kt+=64){
    stage_tile<64,4> (klTh + (ntile << 6)*256 + kt, 256, u.s.Ah, lane, wave);
    stage_tile<64,4> (klTl + (ntile << 6)*256 + kt, 256, u.s.Al, lane, wave);
    stage_tile<256,4>(qTh + ((long long)b << 16) + kt, 256, u.s.Bh, lane, wave);
    stage_tile<256,4>(qTl + ((long long)b << 16) + kt, 256, u.s.Bl, lane, wave);
    __syncthreads();
    #pragma unroll
    for (int kk=0;kk<2;kk++){
      bf16x8 a[4], al[4], bfr[4], bl[4];
      #pragma unroll
      for (int i=0;i<4;i++){
        a[i]   = ldfrag(u.s.Ah, i*16, kk, lane);
        al[i]  = ldfrag(u.s.Al, i*16, kk, lane);
        bfr[i] = ldfrag(u.s.Bh, wave*64 + i*16, kk, lane);
        bl[i]  = ldfrag(u.s.Bl, wave*64 + i*16, kk, lane);
      }
      #pragma unroll
      for (int mt=0;mt<4;mt++)
        #pragma unroll
        for (int nt=0;nt<4;nt++){
          acc[mt][nt] = __builtin_amdgcn_mfma_f32_16x16x32_bf16(a[mt],  bfr[nt], acc[mt][nt], 0,0,0);
          acc[mt][nt] = __builtin_amdgcn_mfma_f32_16x16x32_bf16(al[mt], bfr[nt], acc[mt][nt], 0,0,0);
          acc[mt][nt] = __builtin_amdgcn_mfma_f32_16x16x32_bf16(a[mt],  bl[nt],  acc[mt][nt], 0,0,0);
        }
    }
    __syncthreads();
  }

  // dump logits (K_DIM=1 => scale 1) into L [64][258]
  #pragma unroll
  for (int mt=0;mt<4;mt++)
    #pragma unroll
    for (int nt=0;nt<4;nt++){
      const int r0 = mt*16 + ((lane >> 4) << 2);
      const int c  = wave*64 + nt*16 + (lane & 15);
      #pragma unroll
      for (int rr=0;rr<4;rr++) u.t.L[(r0 + rr)*258 + c] = acc[mt][nt][rr];
    }
  __syncthreads();

  // row max & sum(exp): 4 threads per row
  {
    const int row = tid >> 2, sub = tid & 3;
    const float* Lr = &u.t.L[row*258 + sub*64];
    float mx = -3.4e38f;
    for (int i=0;i<64;i++) mx = fmaxf(mx, Lr[i]);
    mx = fmaxf(mx, __shfl_xor(mx, 1, 64));
    mx = fmaxf(mx, __shfl_xor(mx, 2, 64));
    float s = 0.f;
    for (int i=0;i<64;i++) s += __expf(Lr[i] - mx);
    s += __shfl_xor(s, 1, 64);
    s += __shfl_xor(s, 2, 64);
    if (sub == 0){ u.t.rmax[row] = mx; u.t.rinv[row] = 1.f / s; }
  }
  __syncthreads();

  // transposed store: thread qq writes attT[b][qq][ntile*64 .. +64)
  {
    const int qq = tid;
    u16* dst = attT + ((long long)b << 16) + qq*256 + (ntile << 6);
    #pragma unroll
    for (int n0=0;n0<64;n0+=8){
      bf16x8 pk;
      #pragma unroll
      for (int e=0;e<8;e++){
        int n = n0 + e;
        float v = __expf(u.t.L[n*258 + qq] - u.t.rmax[n]) * u.t.rinv[n];
        pk[e] = (short)f2bf(v);
      }
      *(bf16x8*)(dst + n0) = pk;
    }
  }
}

// fused split of Wq/Wv/Wo into bf16 hi/lo (one launch, 768 blocks;
// bid>>8 selects the weight, bid&255 the 256-f32x4 chunk)
__global__ void k_split3(const float* __restrict__ w0, u16* __restrict__ h0, u16* __restrict__ l0,
                         const float* __restrict__ w1, u16* __restrict__ h1, u16* __restrict__ l1,
                         const float* __restrict__ w2, u16* __restrict__ h2, u16* __restrict__ l2){
  const int which = blockIdx.x >> 8;
  const float* w = (which == 0) ? w0 : (which == 1) ? w1 : w2;
  u16* hi = (which == 0) ? h0 : (which == 1) ? h1 : h2;
  u16* lo = (which == 0) ? l0 : (which == 1) ? l1 : l2;
  int i = (blockIdx.x & 255) * blockDim.x + threadIdx.x;
  f32x4 v = ((const f32x4*)w)[i];
  u16x4 h, l;
  #pragma unroll
  for (int e=0;e<4;e++){
    u16 hh = f2bf(v[e]);
    h[e] = hh;
    l[e] = f2bf(v[e] - bf2f(hh));
  }
  ((u16x4*)hi)[i] = h;
  ((u16x4*)lo)[i] = l;
}

extern "C" void kernel_launch(void* const* d_in, const int* in_sizes, int n_in,
                              void* d_out, int out_size, void* d_ws, size_t ws_size,
                              hipStream_t stream){
  (void)in_sizes; (void)n_in; (void)out_size; (void)ws_size;
  const float* x  = (const float*)d_in[0];
  const float* Wq = (const float*)d_in[1];
  const float* bq = (const float*)d_in[2];
  const float* Wk = (const float*)d_in[3];
  const float* bk = (const float*)d_in[4];
  const float* Wv = (const float*)d_in[5];
  const float* bv = (const float*)d_in[6];
  const float* Wo = (const float*)d_in[7];
  const float* bo = (const float*)d_in[8];

  // scratch carved from d_out (dead before K5 rewrites it) + d_ws
  char* ob = (char*)d_out;
  u16* qTh  = (u16*)(ob);                          // 33.5 MB
  u16* qTl  = (u16*)(ob + (size_t)33554432);       // 33.5 MB
  u16* vh   = (u16*)(ob + (size_t)67108864);       // 33.5 MB
  u16* attT = (u16*)(ob + (size_t)100663296);      // 33.5 MB
  char* wb = (char*)d_ws;
  u16* omh  = (u16*)(wb);                          // 33.5 MB
  u16* Wqh  = (u16*)(wb + (size_t)33554432);
  u16* Wql  = Wqh + 262144;
  u16* Wvh  = Wql + 262144;
  u16* Wvl  = Wvh + 262144;
  u16* Woh  = Wvl + 262144;
  u16* Wol  = Woh + 262144;
  u16* klTh = Wol + 262144;                        // 128 KB
  u16* klTl = klTh + 65536;                        // total ws ~36.9 MB

  k_split3<<<768, 256, 0, stream>>>(Wq, Wqh, Wql, Wv, Wvh, Wvl, Wo, Woh, Wol);

  // fused q(split)/v/klin: reads x once; 80KB LDS -> 2 blocks/CU
  k_qvkl<<<512, 512, 0, stream>>>(x, Wqh, Wql, Wvh, Wk, bk, bq, bv,
                                  qTh, qTl, vh, klTh, klTl);
  // K3: logits + softmax -> attT (XCD-grouped, 80KB LDS)
  k_logits<<<1024, 256, 0, stream>>>(qTh, qTl, klTh, klTl, attT);
  // K4: om = v @ att (B batched per b), N=256, K=256, XCD-grouped
  k_gemm<1,1><<<1024, 256, 0, stream>>>(vh, attT, 256, 256, 2, 65536, nullptr, omh);
  // K5: out = om @ Wo^T + bo (fp32 out), N=1024, K=256, tn-grouped
  k_gemm<0,2><<<4096, 256, 0, stream>>>(omh, Woh, 1024, 256, 8, 0, bo, d_out);
}

// Round 13
// 332.237 us; speedup vs baseline: 1.0379x; 1.0379x over previous
//
#include <hip/hip_runtime.h>

// ---------------------------------------------------------------------------
// Self_Attention_30193620091602  (N=256, A=1024, K_DIM=1), fp32 in/out.
// R13 == R11 exactly (best verified: 334.0us, absmax 4.15e-3).
// R12's single-buffer experiment regressed: the 128-AGPR accumulator caps
// k_qvkl at 1 block/CU regardless of LDS (VGPR_Count excludes AGPRs), so
// dropping the weight dbuf only re-exposed W-DMA latency (-14us). Final
// config: counted-vmcnt weight-dbuf k_qvkl (clean x4), XCD-grouped tail,
// fused weight-split.
// Scratch: d_out[0..134MB) holds qT/v/attT (dead before K5 overwrites d_out);
// d_ws holds om + split weights + klT (~37 MB).
// ---------------------------------------------------------------------------

typedef unsigned short u16;
typedef unsigned int   uint;
using f32x4  = __attribute__((ext_vector_type(4))) float;
using bf16x8 = __attribute__((ext_vector_type(8))) short;
using u16x4  = __attribute__((ext_vector_type(4))) u16;

#define DEVI static __device__ __forceinline__

DEVI u16 f2bf(float f){
  union { float f; uint u; } v; v.f = f;
  uint r = v.u + 0x7fffu + ((v.u >> 16) & 1u);   // round-to-nearest-even
  return (u16)(r >> 16);
}
DEVI float bf2f(u16 h){
  union { uint u; float f; } v; v.u = ((uint)h) << 16;
  return v.f;
}

typedef const uint __attribute__((address_space(1)))* as1_cuintp;
typedef uint __attribute__((address_space(3)))* as3_uintp;

DEVI void gl_lds16(const void* g, void* l){
  __builtin_amdgcn_global_load_lds((as1_cuintp)g, (as3_uintp)l, 16, 0, 0);
}

// Stage ROWS x 64 bf16 tile (rowStride elems in global) into LDS, NW waves.
// LDS layout: elem(row,k) at row*64 + ((k/8 ^ (row&7))*8 + k%8)  (16B-chunk
// XOR swizzle; global_load_lds writes linearly, so the SOURCE is pre-swizzled).
template<int ROWS, int NW>
DEVI void stage_tile(const u16* __restrict__ g, long long rowStride,
                     u16* lds, int lane, int wave){
  constexpr int NLD = ROWS >> 3;            // 1KB wave-loads
  #pragma unroll
  for (int j = 0; j < NLD/NW; ++j){
    int r0  = (wave + NW*j) << 3;
    int row = r0 + (lane >> 3);
    const u16* src = g + (long long)row * rowStride
                       + (((lane & 7) ^ (lane >> 3)) << 3);
    gl_lds16(src, lds + r0 * 64);
  }
}

// MFMA A/B fragment read from the swizzled [*,64] LDS tile.
DEVI bf16x8 ldfrag(const u16* s, int rbase, int kk, int lane){
  int row = rbase + (lane & 15);
  int c   = (kk << 2) + (lane >> 4);
  return *(const bf16x8*)(s + row*64 + ((c ^ (row & 7)) << 3));
}

// ---------------------------------------------------------------------------
// k_qvkl: fused q(split) + v + klin — R6/R9/R11 VERBATIM (clean, ~215us).
// 512 thr, 8 waves 2x4; per phase a wave computes 64 rows x 32 cols.
// Counted-vmcnt weight dbuf: weights for phase p+1 in flight across phase
// p's barriers.  No registers live across barriers.
// ---------------------------------------------------------------------------
__global__ __launch_bounds__(512, 2)
void k_qvkl(const float* __restrict__ x,
            const u16* __restrict__ Wqh, const u16* __restrict__ Wql,
            const u16* __restrict__ Wvh,
            const float* __restrict__ Wk, const float* __restrict__ bk,
            const float* __restrict__ bq, const float* __restrict__ bv,
            u16* __restrict__ qTh, u16* __restrict__ qTl,
            u16* __restrict__ vout,
            u16* __restrict__ klTh, u16* __restrict__ klTl)
{
  __shared__ __align__(16) u16 sX [128*64];        // 16KB  x hi
  __shared__ __align__(16) u16 sXl[128*64];        // 16KB  x lo
  __shared__ __align__(16) u16 sW [2][3*128*64];   // 2 x 48KB: [Wqh|Wql|Wvh] half-N
                                                   // total 128KB

  const int tid  = threadIdx.x;
  const int lane = tid & 63;
  const int wave = tid >> 6;     // 0..7
  const int wm   = wave >> 2;    // 0..1  row-half
  const int wn   = wave & 3;     // 0..3  col-slice within a half
  const int tileM = blockIdx.x << 7;

  f32x4 qacc[4][4], vacc[4][4];  // [mt][ntg], ntg = h*2 + ntl
  #pragma unroll
  for (int i=0;i<4;i++)
    #pragma unroll
    for (int j=0;j<4;j++){
      qacc[i][j][0]=0.f; qacc[i][j][1]=0.f; qacc[i][j][2]=0.f; qacc[i][j][3]=0.f;
      vacc[i][j][0]=0.f; vacc[i][j][1]=0.f; vacc[i][j][2]=0.f; vacc[i][j][3]=0.f;
    }
  float kacc[4] = {0.f, 0.f, 0.f, 0.f};

  // prologue: stage phase-0 weights (kt=0, half 0) into sW[0]
  stage_tile<128,8>(Wqh + 0, 1024, sW[0],         lane, wave);
  stage_tile<128,8>(Wql + 0, 1024, sW[0] + 8192,  lane, wave);
  stage_tile<128,8>(Wvh + 0, 1024, sW[0] + 16384, lane, wave);

  for (int kt = 0; kt < 1024; kt += 64){
    #pragma unroll
    for (int h = 0; h < 2; ++h){          // h compile-time via unroll (rule #20)
      // --- x loads for this kt (h==0 only), ISSUED BEFORE the stage so the
      //     compiler's xr-wait leaves weight DMA in flight.
      f32x4 xr[4];
      if (h == 0){
        #pragma unroll
        for (int j=0;j<4;j++){
          int f = tid + (j << 9);
          xr[j] = *(const f32x4*)(x + (long long)(tileM + (f >> 4))*1024
                                  + kt + ((f & 15) << 2));
        }
        __builtin_amdgcn_sched_barrier(0);   // pin: xr issue before stage issue
      }
      // --- stage NEXT phase's weights into the other buffer (6 gl_lds/wave)
      const bool last = (kt == 960) && (h == 1);
      if (!last){
        const int nh  = h ^ 1;
        const int nkt = (h == 0) ? kt : kt + 64;
        u16* wb = sW[h ^ 1];
        stage_tile<128,8>(Wqh + (nh << 7)*1024 + nkt, 1024, wb,         lane, wave);
        stage_tile<128,8>(Wql + (nh << 7)*1024 + nkt, 1024, wb + 8192,  lane, wave);
        stage_tile<128,8>(Wvh + (nh << 7)*1024 + nkt, 1024, wb + 16384, lane, wave);
      }
      // --- convert x -> sX/sXl, accumulate klin (verbatim R4 math)
      if (h == 0){
        #pragma unroll
        for (int j=0;j<4;j++){
          int f   = tid + (j << 9);
          int row = f >> 4;
          int c16 = f & 15;
          f32x4 t = xr[j];
          u16x4 h4, l4;
          #pragma unroll
          for (int e=0;e<4;e++){
            u16 hh = f2bf(t[e]);
            h4[e] = hh;
            l4[e] = f2bf(t[e] - bf2f(hh));
          }
          int off = row*64 + (((c16 >> 1) ^ (row & 7)) << 3) + ((c16 & 1) << 2);
          *(u16x4*)(sX  + off) = h4;
          *(u16x4*)(sXl + off) = l4;
          f32x4 w = *(const f32x4*)(Wk + kt + (c16 << 2));
          kacc[j] += t[0]*w[0] + t[1]*w[1] + t[2]*w[2] + t[3]*w[3];
        }
      }
      // --- pre-MFMA barrier: THIS phase's weights landed (6 newer in flight),
      //     convert's ds_writes drained.  Never vmcnt(0) except the last phase.
      if (!last) asm volatile("s_waitcnt vmcnt(6) lgkmcnt(0)" ::: "memory");
      else       asm volatile("s_waitcnt vmcnt(0) lgkmcnt(0)" ::: "memory");
      __builtin_amdgcn_s_barrier();
      __builtin_amdgcn_sched_barrier(0);

      // --- MFMA for this half: wave covers cols h*128 + wn*32 + ntl*16
      {
        const u16* wb = sW[h];
        #pragma unroll
        for (int kk=0;kk<2;kk++){
          bf16x8 a[4], al[4];
          #pragma unroll
          for (int i=0;i<4;i++){
            a[i]  = ldfrag(sX , wm*64 + i*16, kk, lane);
            al[i] = ldfrag(sXl, wm*64 + i*16, kk, lane);
          }
          {
            bf16x8 b[2];
            #pragma unroll
            for (int i=0;i<2;i++) b[i] = ldfrag(wb, wn*32 + i*16, kk, lane);
            #pragma unroll
            for (int mt=0;mt<4;mt++)
              #pragma unroll
              for (int ntl=0;ntl<2;ntl++){
                qacc[mt][(h<<1)|ntl] = __builtin_amdgcn_mfma_f32_16x16x32_bf16(a[mt],  b[ntl], qacc[mt][(h<<1)|ntl], 0,0,0);
                qacc[mt][(h<<1)|ntl] = __builtin_amdgcn_mfma_f32_16x16x32_bf16(al[mt], b[ntl], qacc[mt][(h<<1)|ntl], 0,0,0);
              }
          }
          {
            bf16x8 b[2];
            #pragma unroll
            for (int i=0;i<2;i++) b[i] = ldfrag(wb + 8192, wn*32 + i*16, kk, lane);
            #pragma unroll
            for (int mt=0;mt<4;mt++)
              #pragma unroll
              for (int ntl=0;ntl<2;ntl++)
                qacc[mt][(h<<1)|ntl] = __builtin_amdgcn_mfma_f32_16x16x32_bf16(a[mt], b[ntl], qacc[mt][(h<<1)|ntl], 0,0,0);
          }
          {
            bf16x8 b[2];
            #pragma unroll
            for (int i=0;i<2;i++) b[i] = ldfrag(wb + 16384, wn*32 + i*16, kk, lane);
            #pragma unroll
            for (int mt=0;mt<4;mt++)
              #pragma unroll
              for (int ntl=0;ntl<2;ntl++)
                vacc[mt][(h<<1)|ntl] = __builtin_amdgcn_mfma_f32_16x16x32_bf16(a[mt], b[ntl], vacc[mt][(h<<1)|ntl], 0,0,0);
          }
        }
      }
      // --- post-MFMA barrier: all waves' LDS reads done before next phase's
      //     DMA/convert overwrites them.  NO vmcnt here (keep DMA flying).
      asm volatile("s_waitcnt lgkmcnt(0)" ::: "memory");
      __builtin_amdgcn_s_barrier();
      __builtin_amdgcn_sched_barrier(0);
    }
  }

  // klin: reduce over 16-lane groups (each group owns one row per j), store T
  #pragma unroll
  for (int j=0;j<4;j++){
    #pragma unroll
    for (int m=1;m<16;m<<=1) kacc[j] += __shfl_xor(kacc[j], m, 64);
  }
  if ((lane & 15) == 0){
    #pragma unroll
    for (int j=0;j<4;j++){
      int f = tid + (j << 9);
      int r = tileM + (f >> 4);
      float kv = kacc[j] + bk[0];
      u16 hh = f2bf(kv);
      klTh[(r & 255)*256 + (r >> 8)] = hh;
      klTl[(r & 255)*256 + (r >> 8)] = f2bf(kv - bf2f(hh));
    }
  }

  // epilogue: C/D frag col = lane&15, row = (lane>>4)*4 + reg
  // cols: gc = (ntg>>1)*128 + wn*32 + (ntg&1)*16 + (lane&15)
  #pragma unroll
  for (int mt=0;mt<4;mt++)
    #pragma unroll
    for (int ntg=0;ntg<4;ntg++){
      const int gr = tileM + wm*64 + mt*16 + ((lane >> 4) << 2);
      const int gc = ((ntg >> 1) << 7) + wn*32 + ((ntg & 1) << 4) + (lane & 15);
      // qT: transposed hi/lo pair, 4 consecutive m -> 8B store (R1 WMODE=2)
      {
        const int bidx = gr >> 8, m = gr & 255;
        const long long off = ((long long)bidx << 16) + ((long long)gc << 8) + m;
        const float bb = bq[gc];
        u16x4 h4, l4;
        f32x4 v = qacc[mt][ntg];
        #pragma unroll
        for (int r=0;r<4;r++){
          float fq = v[r] + bb;
          u16 hh = f2bf(fq);
          h4[r] = hh;
          l4[r] = f2bf(fq - bf2f(hh));
        }
        *(u16x4*)(qTh + off) = h4;
        *(u16x4*)(qTl + off) = l4;
      }
      // v: natural bf16 (R1 WMODE=1)
      {
        const float bb = bv[gc];
        u16* o = vout + (long long)gr * 256 + gc;
        f32x4 v = vacc[mt][ntg];
        #pragma unroll
        for (int r=0;r<4;r++) o[(long long)r * 256] = f2bf(v[r] + bb);
      }
    }
}

// ---------------------------------------------------------------------------
// Generic GEMM: C[M x N] = A[M x K] * B^T (B stored N x K) (+bias)
// WMODE: 0 = fp32 natural (+bias)   (out-proj)
//        1 = bf16 natural (+bias)   (om)
// SWZ:   0 = none
//        1 = K4 grouping: 4 blocks sharing (vh tile pair, attT[b]) -> 1 XCD
//        2 = K5 grouping: 8 tn-blocks sharing an A tile -> 1 XCD
// bStrideB: if nonzero, B is batched per b = row/256 (attT).
// ---------------------------------------------------------------------------
template<int WMODE, int SWZ>
__global__ __launch_bounds__(256, 2)
void k_gemm(const u16* __restrict__ Ag,
            const u16* __restrict__ Bhg,
            int N, int K, int tnCount, long long bStrideB,
            const float* __restrict__ bias,
            void* __restrict__ Co)
{
  __shared__ __align__(16) u16 sA[128*64];
  __shared__ __align__(16) u16 sB[128*64];

  const int tid  = threadIdx.x;
  const int lane = tid & 63;
  const int wave = tid >> 6;
  const int wm   = wave >> 1;
  const int wn   = wave & 1;

  int tm, tn;
  if (SWZ == 1){
    const int bid = blockIdx.x;
    const int xcd = bid & 7, r = bid >> 3;
    const int inner = r & 3, slot = r >> 2;
    const int b = slot*8 + xcd;
    tm = 2*b + (inner >> 1);
    tn = inner & 1;
  } else if (SWZ == 2){
    const int bid = blockIdx.x;
    const int xcd = bid & 7, r = bid >> 3;
    tn = r & 7;
    tm = (r >> 3)*8 + xcd;
  } else {
    tn = blockIdx.x % tnCount;
    tm = blockIdx.x / tnCount;
  }
  const int tileM = tm << 7;
  const int tileN = tn << 7;

  const long long bOff = bStrideB ? (long long)(tileM >> 8) * bStrideB : 0;
  const u16* Bh_t = Bhg + bOff + (long long)tileN * K;

  f32x4 acc[4][4];
  #pragma unroll
  for (int i=0;i<4;i++)
    #pragma unroll
    for (int j=0;j<4;j++){
      acc[i][j][0]=0.f; acc[i][j][1]=0.f; acc[i][j][2]=0.f; acc[i][j][3]=0.f;
    }

  for (int kt = 0; kt < K; kt += 64){
    stage_tile<128,4>(Ag + (long long)tileM * K + kt, K, sA, lane, wave);
    stage_tile<128,4>(Bh_t + kt, K, sB, lane, wave);
    __syncthreads();
    #pragma unroll
    for (int kk=0;kk<2;kk++){
      bf16x8 a[4], b[4];
      #pragma unroll
      for (int i=0;i<4;i++){
        a[i] = ldfrag(sA, wm*64 + i*16, kk, lane);
        b[i] = ldfrag(sB, wn*64 + i*16, kk, lane);
      }
      #pragma unroll
      for (int mt=0;mt<4;mt++)
        #pragma unroll
        for (int nt=0;nt<4;nt++)
          acc[mt][nt] = __builtin_amdgcn_mfma_f32_16x16x32_bf16(a[mt], b[nt], acc[mt][nt], 0,0,0);
    }
    __syncthreads();
  }

  #pragma unroll
  for (int mt=0;mt<4;mt++)
    #pragma unroll
    for (int nt=0;nt<4;nt++){
      const int gr = tileM + wm*64 + mt*16 + ((lane >> 4) << 2);
      const int gc = tileN + wn*64 + nt*16 + (lane & 15);
      const float bb = bias ? bias[gc] : 0.f;
      f32x4 v = acc[mt][nt];
      if (WMODE == 0){
        float* o = (float*)Co + (long long)gr * N + gc;
        #pragma unroll
        for (int r=0;r<4;r++) o[(long long)r * N] = v[r] + bb;
      } else {
        u16* o = (u16*)Co + (long long)gr * N + gc;
        #pragma unroll
        for (int r=0;r<4;r++) o[(long long)r * N] = f2bf(v[r] + bb);
      }
    }
}

// ---------------------------------------------------------------------------
// K3: logits[b,n,:] = sum_m klT[n][m] * qT[b][:,m]  (split 3-pass), then
// row-softmax over qq (full 256 in-block), store attT[b][qq][n] bf16.
// Block = (b, ntile) via XCD-grouping swizzle; LDS 80KB -> 2 blocks/CU.
// ---------------------------------------------------------------------------
__global__ __launch_bounds__(256, 2)
void k_logits(const u16* __restrict__ qTh, const u16* __restrict__ qTl,
              const u16* __restrict__ klTh, const u16* __restrict__ klTl,
              u16* __restrict__ attT)
{
  __shared__ __align__(16) union U {
    struct S { u16 Ah[64*64]; u16 Al[64*64]; u16 Bh[256*64]; u16 Bl[256*64]; } s; // 81920 B
    struct T { float L[64*258]; float rmax[64]; float rinv[64]; } t;              // 66560 B
  } u;                                                                            // 80 KB

  const int tid  = threadIdx.x;
  const int lane = tid & 63;
  const int wave = tid >> 6;
  // XCD-grouping swizzle: bid = xcd + 8*(ntile + 4*slot); b = slot*8 + xcd
  const int bid   = blockIdx.x;
  const int xcd   = bid & 7, r = bid >> 3;
  const int ntile = r & 3;
  const int b     = (r >> 2)*8 + xcd;

  f32x4 acc[4][4];
  #pragma unroll
  for (int i=0;i<4;i++)
    #pragma unroll
    for (int j=0;j<4;j++){
      acc[i][j][0]=0.f; acc[i][j][1]=0.f; acc[i][j][2]=0.f; acc[i][j][3]=0.f;
    }

  for (int kt=0; kt<256; kt+=64){
    stage_tile<64,4> (klTh + (ntile << 6)*256 + kt, 256, u.s.Ah, lane, wave);
    stage_tile<64,4> (klTl + (ntile << 6)*256 + kt, 256, u.s.Al, lane, wave);
    stage_tile<256,4>(qTh + ((long long)b << 16) + kt, 256, u.s.Bh, lane, wave);
    stage_tile<256,4>(qTl + ((long long)b << 16) + kt, 256, u.s.Bl, lane, wave);
    __syncthreads();
    #pragma unroll
    for (int kk=0;kk<2;kk++){
      bf16x8 a[4], al[4], bfr[4], bl[4];
      #pragma unroll
      for (int i=0;i<4;i++){
        a[i]   = ldfrag(u.s.Ah, i*16, kk, lane);
        al[i]  = ldfrag(u.s.Al, i*16, kk, lane);
        bfr[i] = ldfrag(u.s.Bh, wave*64 + i*16, kk, lane);
        bl[i]  = ldfrag(u.s.Bl, wave*64 + i*16, kk, lane);
      }
      #pragma unroll
      for (int mt=0;mt<4;mt++)
        #pragma unroll
        for (int nt=0;nt<4;nt++){
          acc[mt][nt] = __builtin_amdgcn_mfma_f32_16x16x32_bf16(a[mt],  bfr[nt], acc[mt][nt], 0,0,0);
          acc[mt][nt] = __builtin_amdgcn_mfma_f32_16x16x32_bf16(al[mt], bfr[nt], acc[mt][nt], 0,0,0);
          acc[mt][nt] = __builtin_amdgcn_mfma_f32_16x16x32_bf16(a[mt],  bl[nt],  acc[mt][nt], 0,0,0);
        }
    }
    __syncthreads();
  }

  // dump logits (K_DIM=1 => scale 1) into L [64][258]
  #pragma unroll
  for (int mt=0;mt<4;mt++)
    #pragma unroll
    for (int nt=0;nt<4;nt++){
      const int r0 = mt*16 + ((lane >> 4) << 2);
      const int c  = wave*64 + nt*16 + (lane & 15);
      #pragma unroll
      for (int rr=0;rr<4;rr++) u.t.L[(r0 + rr)*258 + c] = acc[mt][nt][rr];
    }
  __syncthreads();

  // row max & sum(exp): 4 threads per row
  {
    const int row = tid >> 2, sub = tid & 3;
    const float* Lr = &u.t.L[row*258 + sub*64];
    float mx = -3.4e38f;
    for (int i=0;i<64;i++) mx = fmaxf(mx, Lr[i]);
    mx = fmaxf(mx, __shfl_xor(mx, 1, 64));
    mx = fmaxf(mx, __shfl_xor(mx, 2, 64));
    float s = 0.f;
    for (int i=0;i<64;i++) s += __expf(Lr[i] - mx);
    s += __shfl_xor(s, 1, 64);
    s += __shfl_xor(s, 2, 64);
    if (sub == 0){ u.t.rmax[row] = mx; u.t.rinv[row] = 1.f / s; }
  }
  __syncthreads();

  // transposed store: thread qq writes attT[b][qq][ntile*64 .. +64)
  {
    const int qq = tid;
    u16* dst = attT + ((long long)b << 16) + qq*256 + (ntile << 6);
    #pragma unroll
    for (int n0=0;n0<64;n0+=8){
      bf16x8 pk;
      #pragma unroll
      for (int e=0;e<8;e++){
        int n = n0 + e;
        float v = __expf(u.t.L[n*258 + qq] - u.t.rmax[n]) * u.t.rinv[n];
        pk[e] = (short)f2bf(v);
      }
      *(bf16x8*)(dst + n0) = pk;
    }
  }
}

// fused split of Wq/Wv/Wo into bf16 hi/lo (one launch, 768 blocks;
// bid>>8 selects the weight, bid&255 the 256-f32x4 chunk)
__global__ void k_split3(const float* __restrict__ w0, u16* __restrict__ h0, u16* __restrict__ l0,
                         const float* __restrict__ w1, u16* __restrict__ h1, u16* __restrict__ l1,
                         const float* __restrict__ w2, u16* __restrict__ h2, u16* __restrict__ l2){
  const int which = blockIdx.x >> 8;
  const float* w = (which == 0) ? w0 : (which == 1) ? w1 : w2;
  u16* hi = (which == 0) ? h0 : (which == 1) ? h1 : h2;
  u16* lo = (which == 0) ? l0 : (which == 1) ? l1 : l2;
  int i = (blockIdx.x & 255) * blockDim.x + threadIdx.x;
  f32x4 v = ((const f32x4*)w)[i];
  u16x4 h, l;
  #pragma unroll
  for (int e=0;e<4;e++){
    u16 hh = f2bf(v[e]);
    h[e] = hh;
    l[e] = f2bf(v[e] - bf2f(hh));
  }
  ((u16x4*)hi)[i] = h;
  ((u16x4*)lo)[i] = l;
}

extern "C" void kernel_launch(void* const* d_in, const int* in_sizes, int n_in,
                              void* d_out, int out_size, void* d_ws, size_t ws_size,
                              hipStream_t stream){
  (void)in_sizes; (void)n_in; (void)out_size; (void)ws_size;
  const float* x  = (const float*)d_in[0];
  const float* Wq = (const float*)d_in[1];
  const float* bq = (const float*)d_in[2];
  const float* Wk = (const float*)d_in[3];
  const float* bk = (const float*)d_in[4];
  const float* Wv = (const float*)d_in[5];
  const float* bv = (const float*)d_in[6];
  const float* Wo = (const float*)d_in[7];
  const float* bo = (const float*)d_in[8];

  // scratch carved from d_out (dead before K5 rewrites it) + d_ws
  char* ob = (char*)d_out;
  u16* qTh  = (u16*)(ob);                          // 33.5 MB
  u16* qTl  = (u16*)(ob + (size_t)33554432);       // 33.5 MB
  u16* vh   = (u16*)(ob + (size_t)67108864);       // 33.5 MB
  u16* attT = (u16*)(ob + (size_t)100663296);      // 33.5 MB
  char* wb = (char*)d_ws;
  u16* omh  = (u16*)(wb);                          // 33.5 MB
  u16* Wqh  = (u16*)(wb + (size_t)33554432);
  u16* Wql  = Wqh + 262144;
  u16* Wvh  = Wql + 262144;
  u16* Wvl  = Wvh + 262144;
  u16* Woh  = Wvl + 262144;
  u16* Wol  = Woh + 262144;
  u16* klTh = Wol + 262144;                        // 128 KB
  u16* klTl = klTh + 65536;                        // total ws ~36.9 MB

  k_split3<<<768, 256, 0, stream>>>(Wq, Wqh, Wql, Wv, Wvh, Wvl, Wo, Woh, Wol);

  // fused q(split)/v/klin: reads x once (R6/R9/R11-verbatim kernel)
  k_qvkl<<<512, 512, 0, stream>>>(x, Wqh, Wql, Wvh, Wk, bk, bq, bv,
                                  qTh, qTl, vh, klTh, klTl);
  // K3: logits + softmax -> attT (XCD-grouped, 80KB LDS)
  k_logits<<<1024, 256, 0, stream>>>(qTh, qTl, klTh, klTl, attT);
  // K4: om = v @ att (B batched per b), N=256, K=256, XCD-grouped
  k_gemm<1,1><<<1024, 256, 0, stream>>>(vh, attT, 256, 256, 2, 65536, nullptr, omh);
  // K5: out = om @ Wo^T + bo (fp32 out), N=1024, K=256, tn-grouped
  k_gemm<0,2><<<4096, 256, 0, stream>>>(omh, Woh, 1024, 256, 8, 0, bo, d_out);
}